// Round 12
// baseline (164.334 us; speedup 1.0000x reference)
//
#include <hip/hip_runtime.h>
#include <stdint.h>

#define HBINS 8192
#define HSHIFT 19
#define CAND 2048
#define STHREADS 1024

typedef unsigned int u32;
typedef unsigned long long u64;

// order-preserving float->uint map (ascending uint == ascending float)
__device__ __forceinline__ u32 f2s(float f) {
  u32 b = __float_as_uint(f);
  return b ^ ((b & 0x80000000u) ? 0xFFFFFFFFu : 0x80000000u);
}
__device__ __forceinline__ float s2f(u32 s) {
  u32 b = (s & 0x80000000u) ? (s ^ 0x80000000u) : ~s;
  return __uint_as_float(b);
}
__device__ __forceinline__ u32 rotl32(u32 x, int r) { return (x << r) | (x >> (32 - r)); }

__device__ __forceinline__ u64 shfl_xor_u64(u64 v, int mask) {
  int lo = __shfl_xor((int)(u32)v, mask, 64);
  int hi = __shfl_xor((int)(u32)(v >> 32), mask, 64);
  return ((u64)(u32)hi << 32) | (u32)lo;
}
__device__ __forceinline__ u64 shfl_down_u64(u64 v, int delta) {
  int lo = __shfl_down((int)(u32)v, delta, 64);
  int hi = __shfl_down((int)(u32)(v >> 32), delta, 64);
  return ((u64)(u32)hi << 32) | (u32)lo;
}

// JAX threefry2x32, partitionable counter mode, key = jax.random.key(42) -> (0,42).
__device__ __forceinline__ u32 threefry_bits(u32 ctr) {
  const u32 ks0 = 0u, ks1 = 42u, ks2 = 0x1BD11BDAu ^ 0u ^ 42u;
  u32 x0 = ks0;
  u32 x1 = ctr + ks1;
#define TFR(r) { x0 += x1; x1 = rotl32(x1, (r)); x1 ^= x0; }
  TFR(13) TFR(15) TFR(26) TFR(6)   x0 += ks1; x1 += ks2 + 1u;
  TFR(17) TFR(29) TFR(16) TFR(24)  x0 += ks2; x1 += ks0 + 2u;
  TFR(13) TFR(15) TFR(26) TFR(6)   x0 += ks0; x1 += ks1 + 3u;
  TFR(17) TFR(29) TFR(16) TFR(24)  x0 += ks1; x1 += ks2 + 4u;
  TFR(13) TFR(15) TFR(26) TFR(6)   x0 += ks2; x1 += ks0 + 5u;
#undef TFR
  return x0 ^ x1;
}

// ---------------- fully fused per-row pipeline (one block per row) -----------
// hist -> select -> collect -> sort -> softmax chain -> gumbel, all row-local.
// Round-12 change: 8-deep register batching of the two streaming loops (load
// ILP: 8 float4 loads in flight per wave before dependent use) and wave-
// aggregated candidate append (ballot + leader atomicAdd + prefix popcount).
// Candidate order in cand[] is arbitrary either way; the bitonic sort key
// (val<<32)|idx is a total order so the sorted result is bit-identical.
__global__ __launch_bounds__(STHREADS)
void Sampler_73529840107542_kernel(const float* __restrict__ logits,
                                   const float* __restrict__ temps,
                                   const float* __restrict__ minps,
                                   const float* __restrict__ topps,
                                   const int* __restrict__ topks,
                                   int* __restrict__ out, int V) {
  const int row = blockIdx.x;
  const int tid = threadIdx.x;
  const int w = tid >> 6;
  const int l = tid & 63;

  __shared__ __align__(16) unsigned char arena[69632];   // 68 KB
  u32* hp     = (u32*)arena;                 // [0,65536)  phase 1-2
  u32* part   = (u32*)(arena + 65536);       // [65536,69632) phase 2
  u64* cand   = (u64*)arena;                 // [0,16384)  phase 3+
  float* bufA = (float*)(arena + 16384);     // e
  float* bufB = (float*)(arena + 24576);     // cumsum
  unsigned char* keepf = arena + 32768;
  u64* red64  = (u64*)(arena + 16384);       // argmax stage (aliases bufA)
  float* redA = (float*)(arena + 16384);     // Z2 stage
  float* redB = (float*)(arena + 24576);     // Z1 stage

  __shared__ int sh_pstar, sh_cnt, sh_lb, sh_cs;
  __shared__ u32 sh_thr, sh_Ts;
  __shared__ float sh_m, sh_Z1, sh_Z2;

  // ---------------- phase 1: 8192-bin raw-logit histogram ----------------
  for (int i = tid; i < 2 * HBINS; i += STHREADS) hp[i] = 0u;
  __syncthreads();
  const float* src = logits + (size_t)row * (size_t)V;
  const u32 pc = (u32)(tid & 1);             // parity copy to halve atomic trains
  const int n4 = V >> 2;
  const float4* p4 = (const float4*)src;
  const int BB = STHREADS * 8;
  for (int base_i = 0; base_i < n4; base_i += BB) {
    float4 v[8];
    bool ok[8];
#pragma unroll
    for (int j = 0; j < 8; ++j) {
      int i = base_i + j * STHREADS + tid;
      ok[j] = (i < n4);
      v[j] = ok[j] ? p4[i] : float4{0.f, 0.f, 0.f, 0.f};
    }
#pragma unroll
    for (int j = 0; j < 8; ++j) {
      if (ok[j]) {
        atomicAdd(&hp[((f2s(v[j].x) >> HSHIFT) << 1) | pc], 1u);
        atomicAdd(&hp[((f2s(v[j].y) >> HSHIFT) << 1) | pc], 1u);
        atomicAdd(&hp[((f2s(v[j].z) >> HSHIFT) << 1) | pc], 1u);
        atomicAdd(&hp[((f2s(v[j].w) >> HSHIFT) << 1) | pc], 1u);
      }
    }
  }
  for (int i = (n4 << 2) + tid; i < V; i += STHREADS)
    atomicAdd(&hp[((f2s(src[i]) >> HSHIFT) << 1) | pc], 1u);
  __syncthreads();

  // ---------------- phase 2: top-k bin threshold (suffix-scan select) -----
  {
    u32 s = 0;
#pragma unroll
    for (int j = 0; j < 16; ++j) s += hp[tid * 16 + j];   // bins [tid*8, tid*8+8)
    part[tid] = s;
  }
  __syncthreads();
  for (int st = 1; st < STHREADS; st <<= 1) {             // suffix scan
    u32 v = (tid + st < STHREADS) ? part[tid + st] : 0u;
    __syncthreads();
    part[tid] += v;
    __syncthreads();
  }
  int k = topks[row];
  if (k < 1) k = 1;
  if (k > V) k = V;
  const u32 ku = (u32)k;
  if (part[tid] >= ku && (tid == STHREADS - 1 || part[tid + 1] < ku))
    sh_pstar = tid;
  __syncthreads();
  {
    const int pstar = sh_pstar;
    const u32 tail = (pstar < STHREADS - 1) ? part[pstar + 1] : 0u;
    if (tid < 8) {
      u32 sb = tail;                          // suffix count from bin pstar*8+tid
      for (int j = 7; j >= tid; --j) sb += hp[(pstar * 8 + j) * 2] + hp[(pstar * 8 + j) * 2 + 1];
      u32 own = hp[(pstar * 8 + tid) * 2] + hp[(pstar * 8 + tid) * 2 + 1];
      if (sb >= ku && (tid == 7 || sb - own < ku)) {
        sh_thr = (u32)(pstar * 8 + tid) << HSHIFT;
        sh_cs = (int)((sb < (u32)CAND) ? sb : (u32)CAND);
      }
    }
    if (tid == 0) sh_cnt = 0;
  }
  __syncthreads();

  // ---------------- phase 3: collect candidates into LDS cand ------------
  // 8-deep load batching + wave-aggregated append. cand aliases hp (dead).
  const u32 thr = sh_thr;
  const float t = temps[row];
  for (int base_i = 0; base_i < n4; base_i += BB) {
    float4 v[8];
    bool ok[8];
#pragma unroll
    for (int j = 0; j < 8; ++j) {
      int i = base_i + j * STHREADS + tid;
      ok[j] = (i < n4);
      v[j] = ok[j] ? p4[i] : float4{0.f, 0.f, 0.f, 0.f};
    }
#pragma unroll
    for (int j = 0; j < 8; ++j) {
      const int i = base_i + j * STHREADS + tid;
      float vals[4] = {v[j].x, v[j].y, v[j].z, v[j].w};
#pragma unroll
      for (int cmp = 0; cmp < 4; ++cmp) {
        bool pred = ok[j] && (f2s(vals[cmp]) >= thr);
        u64 mk = __ballot(pred);
        if (mk) {
          int leader = __ffsll((long long)mk) - 1;
          int tot = __popcll(mk);
          int b0 = 0;
          if (l == leader) b0 = atomicAdd(&sh_cnt, tot);
          b0 = __shfl(b0, leader, 64);
          if (pred) {
            int pos = b0 + __popcll(mk & ((1ull << l) - 1ull));
            if (pos < CAND)
              cand[pos] = ((u64)f2s(vals[cmp] / t) << 32) | (u32)(4 * i + cmp);
          }
        }
      }
    }
  }
  for (int i = (n4 << 2) + tid; i < V; i += STHREADS) {
    float x = src[i];
    if (f2s(x) >= thr) { int pos = atomicAdd(&sh_cnt, 1); if (pos < CAND) cand[pos] = ((u64)f2s(x / t) << 32) | (u32)i; }
  }
  __syncthreads();
  const int cs = sh_cs;

  // ---------------- phase 4: bitonic sort (unchanged) ---------------------
  const float one_minus_p = 1.0f - topps[row];
  const float minp = minps[row];
  const int e_lo = (w << 7) + l;
  const int e_hi = e_lo + 64;
  const u64 SENT = 0xFFFFFFFFFFFFFFFFull;
  u64 k0 = (e_lo < cs) ? cand[e_lo] : SENT;
  u64 k1 = (e_hi < cs) ? cand[e_hi] : SENT;
  __syncthreads();   // all initial cand reads complete before sort overwrites

  int P = 64;
  while (P < cs) P <<= 1;
  for (int size = 2; size <= P; size <<= 1) {
    for (int s = size >> 1; s > 0; s >>= 1) {
      if (s >= 128) {
        cand[e_lo] = k0; cand[e_hi] = k1;
        __syncthreads();
        u64 p0 = cand[e_lo ^ s], p1 = cand[e_hi ^ s];
        {
          bool keepmin = (((e_lo & s) == 0) == ((e_lo & size) == 0));
          if (keepmin ? (p0 < k0) : (p0 > k0)) k0 = p0;
        }
        {
          bool keepmin = (((e_hi & s) == 0) == ((e_hi & size) == 0));
          if (keepmin ? (p1 < k1) : (p1 > k1)) k1 = p1;
        }
        __syncthreads();
      } else if (s == 64) {
        bool asc = ((e_lo & size) == 0);
        if ((k0 > k1) == asc) { u64 tt = k0; k0 = k1; k1 = tt; }
      } else {
        u64 p0 = shfl_xor_u64(k0, s);
        u64 p1 = shfl_xor_u64(k1, s);
        {
          bool keepmin = (((l & s) == 0) == ((e_lo & size) == 0));
          if (keepmin ? (p0 < k0) : (p0 > k0)) k0 = p0;
        }
        {
          bool keepmin = (((l & s) == 0) == ((e_hi & size) == 0));
          if (keepmin ? (p1 < k1) : (p1 > k1)) k1 = p1;
        }
      }
    }
  }
  cand[e_lo] = k0; cand[e_hi] = k1;
  __syncthreads();

  // ---------------- phase 5+: softmax chain (identical to round 10/11) ----
  if (tid == 0) {
    int ti = cs - k; if (ti < 0) ti = 0;
    sh_Ts = (u32)(cand[ti] >> 32);             // k-th largest x (exact)
    sh_m  = s2f((u32)(cand[cs - 1] >> 32));    // row max
  }
  __syncthreads();
  const u32 Ts = sh_Ts;
  const float m = sh_m;

  for (int c = tid; c < cs; c += STHREADS) {
    u32 s = (u32)(cand[c] >> 32);
    if (s >= Ts && (c == 0 || (u32)(cand[c - 1] >> 32) < Ts)) sh_lb = c;
  }
  __syncthreads();
  const int lb = sh_lb;

  // fused exp + Z1 level 0
  {
    float e0 = 0.0f, e1 = 0.0f;
    const int c0 = tid, c1 = tid + STHREADS;
    if (c0 < cs) {
      u32 s = (u32)(cand[c0] >> 32);
      if (s >= Ts) e0 = expf(s2f(s) - m);
    }
    if (c1 < cs) {
      u32 s = (u32)(cand[c1] >> 32);
      if (s >= Ts) e1 = expf(s2f(s) - m);
    }
    bufA[c0] = e0;
    bufA[c1] = e1;
    redB[tid] = e0 + e1;
  }
  __syncthreads();
  for (int s = STHREADS >> 1; s >= 64; s >>= 1) {
    if (tid < s) redB[tid] += redB[tid + s];
    __syncthreads();
  }
  if (w == 0) {
    float v = redB[l];
    v += __shfl_down(v, 32, 64);
    v += __shfl_down(v, 16, 64);
    v += __shfl_down(v, 8, 64);
    v += __shfl_down(v, 4, 64);
    v += __shfl_down(v, 2, 64);
    v += __shfl_down(v, 1, 64);
    if (l == 0) sh_Z1 = v;
  }
  __syncthreads();
  const float Z1 = sh_Z1;

  // exact sequential cumsum over p = e/Z1 (readlane broadcast, wave 0)
  if (w == 0) {
    float carry = 0.0f;
    for (int base = lb; base < cs; base += 64) {
      int c = base + l;
      float v = (c < cs) ? bufA[c] / Z1 : 0.0f;
      u32 vb = __float_as_uint(v);
      float acc = carry;
#pragma unroll
      for (int j = 0; j < 64; ++j) {
        float tt = __uint_as_float(__builtin_amdgcn_readlane(vb, j));
        acc += (l >= j) ? tt : 0.0f;
      }
      if (c < cs) bufB[c] = acc;
      carry = __uint_as_float(__builtin_amdgcn_readlane(__float_as_uint(acc), 63));
    }
  }
  __syncthreads();

  // fused top-p keep flags + Z2 accumulation
  {
    float local = 0.0f;
    for (int c = tid; c < CAND; c += STHREADS) {
      unsigned char kf = 0;
      if (c < cs) {
        u32 s = (u32)(cand[c] >> 32);
        if (s >= Ts && (c == cs - 1 || bufB[c] > one_minus_p)) kf = 1;
        if (kf) local += expf(s2f(s) - m);
      }
      keepf[c] = kf;
    }
    redA[tid] = local;
  }
  __syncthreads();
  for (int s = STHREADS >> 1; s >= 64; s >>= 1) {
    if (tid < s) redA[tid] += redA[tid + s];
    __syncthreads();
  }
  if (w == 0) {
    float v = redA[l];
    v += __shfl_down(v, 32, 64);
    v += __shfl_down(v, 16, 64);
    v += __shfl_down(v, 8, 64);
    v += __shfl_down(v, 4, 64);
    v += __shfl_down(v, 2, 64);
    v += __shfl_down(v, 1, 64);
    if (l == 0) sh_Z2 = v;
  }
  __syncthreads();

  // min_p
  {
    const float Z2 = sh_Z2;
    const float rhs = minp * (1.0f / Z2);
    for (int c = tid; c < CAND; c += STHREADS) {
      if (keepf[c]) {
        u32 s = (u32)(cand[c] >> 32);
        float p2 = expf(s2f(s) - m) / Z2;
        if (p2 < rhs) keepf[c] = 0;
      }
    }
  }
  __syncthreads();

  // gumbel-max (JAX categorical), first-index tie-break
  {
    const float TINY = 1.17549435082228750797e-38f;
    u64 best = 0ull;
    for (int c = lb + tid; c < cs; c += STHREADS) {
      if (!keepf[c]) continue;
      u32 s = (u32)(cand[c] >> 32);
      u32 idx = (u32)(cand[c] & 0xFFFFFFFFull);
      float x = s2f(s);
      u32 bits = threefry_bits((u32)row * (u32)V + idx);
      float f = __uint_as_float((bits >> 9) | 0x3f800000u) - 1.0f;
      float u = fmaxf(TINY, f * 1.0f + TINY);
      float g = -logf(-logf(u));
      float sc = g + x;
      u64 key = ((u64)f2s(sc) << 32) | (u64)(0xFFFFFFFFu - idx);
      if (key > best) best = key;
    }
    red64[tid] = best;
    __syncthreads();
    for (int s = STHREADS >> 1; s >= 64; s >>= 1) {
      if (tid < s) { u64 o = red64[tid + s]; if (o > red64[tid]) red64[tid] = o; }
      __syncthreads();
    }
    if (w == 0) {
      u64 v = red64[l];
#pragma unroll
      for (int d = 32; d >= 1; d >>= 1) {
        u64 o = shfl_down_u64(v, d);
        if (o > v) v = o;
      }
      if (l == 0) out[row] = (int)(0xFFFFFFFFu - (u32)(v & 0xFFFFFFFFull));
    }
  }
}

extern "C" void kernel_launch(void* const* d_in, const int* in_sizes, int n_in,
                              void* d_out, int out_size, void* d_ws, size_t ws_size,
                              hipStream_t stream) {
  const float* logits = (const float*)d_in[0];
  const float* temps  = (const float*)d_in[1];
  const float* minps  = (const float*)d_in[2];
  const float* topps  = (const float*)d_in[3];
  const int*   topks  = (const int*)d_in[4];
  const int B = in_sizes[1];
  const int V = in_sizes[0] / B;
  (void)n_in; (void)out_size; (void)d_ws; (void)ws_size;

  Sampler_73529840107542_kernel<<<dim3(B), dim3(STHREADS), 0, stream>>>(
      logits, temps, minps, topps, topks, (int*)d_out, V);
}